// Round 1
// baseline (424.968 us; speedup 1.0000x reference)
//
#include <hip/hip_runtime.h>

#define NUM_THRESHOLDS 15

__global__ __launch_bounds__(256) void kmeans_quant_fwd(
    const float* __restrict__ x,
    const float* __restrict__ thresholds,
    const float* __restrict__ alphas,
    const float* __restrict__ b_ptr,
    float* __restrict__ out,
    int n4)
{
    // Uniform scalar parameters — broadcast loads, cached.
    float th[NUM_THRESHOLDS], al[NUM_THRESHOLDS];
#pragma unroll
    for (int i = 0; i < NUM_THRESHOLDS; ++i) {
        th[i] = thresholds[i];
        al[i] = alphas[i];
    }
    const float b = b_ptr[0];

    int i = blockIdx.x * blockDim.x + threadIdx.x;
    if (i >= n4) return;

    const float4* __restrict__ x4 = (const float4*)x;
    float4* __restrict__ o4 = (float4*)out;

    float4 v = x4[i];
    float4 y = make_float4(b, b, b, b);
#pragma unroll
    for (int t = 0; t < NUM_THRESHOLDS; ++t) {
        y.x += (v.x >= th[t]) ? al[t] : 0.0f;
        y.y += (v.y >= th[t]) ? al[t] : 0.0f;
        y.z += (v.z >= th[t]) ? al[t] : 0.0f;
        y.w += (v.w >= th[t]) ? al[t] : 0.0f;
    }
    o4[i] = y;
}

extern "C" void kernel_launch(void* const* d_in, const int* in_sizes, int n_in,
                              void* d_out, int out_size, void* d_ws, size_t ws_size,
                              hipStream_t stream) {
    // setup_inputs order: x, T, thresholds, alphas, b
    const float* x          = (const float*)d_in[0];
    // d_in[1] is T — only used in backward; unused here.
    const float* thresholds = (const float*)d_in[2];
    const float* alphas     = (const float*)d_in[3];
    const float* b          = (const float*)d_in[4];
    float* out              = (float*)d_out;

    const int n = in_sizes[0];          // 32*4096*512 = 67108864, divisible by 4
    const int n4 = n / 4;               // 16777216 float4 elements

    const int block = 256;
    const int grid = (n4 + block - 1) / block;  // 65536 blocks

    kmeans_quant_fwd<<<grid, block, 0, stream>>>(x, thresholds, alphas, b, out, n4);
}

// Round 3
// 421.128 us; speedup vs baseline: 1.0091x; 1.0091x over previous
//
#include <hip/hip_runtime.h>

#define NUM_THRESHOLDS 15

// Native clang vector type — required for __builtin_nontemporal_load/store
// (HIP's float4 is a struct and is rejected by the builtin).
typedef float fvec4 __attribute__((ext_vector_type(4)));

__global__ __launch_bounds__(256) void kmeans_quant_fwd(
    const float* __restrict__ x,
    const float* __restrict__ thresholds,
    const float* __restrict__ alphas,
    const float* __restrict__ b_ptr,
    float* __restrict__ out,
    int n4)  // number of fvec4 elements
{
    // Uniform scalar parameters — broadcast loads, cached.
    float th[NUM_THRESHOLDS], al[NUM_THRESHOLDS];
#pragma unroll
    for (int i = 0; i < NUM_THRESHOLDS; ++i) {
        th[i] = thresholds[i];
        al[i] = alphas[i];
    }
    const float b = b_ptr[0];

    const fvec4* __restrict__ x4 = (const fvec4*)x;
    fvec4* __restrict__ o4 = (fvec4*)out;

    // Each thread handles 2 fvec4 (32 B); within each half lanes are
    // coalesced (consecutive lanes -> consecutive 16 B segments).
    const int base = blockIdx.x * (blockDim.x * 2) + threadIdx.x;

    int i0 = base;
    int i1 = base + blockDim.x;

    if (i1 < n4) {
        // Fast path: both in range. Issue both loads before any compute.
        fvec4 v0 = __builtin_nontemporal_load(&x4[i0]);
        fvec4 v1 = __builtin_nontemporal_load(&x4[i1]);

        fvec4 y0 = {b, b, b, b};
        fvec4 y1 = {b, b, b, b};
#pragma unroll
        for (int t = 0; t < NUM_THRESHOLDS; ++t) {
            y0.x += (v0.x >= th[t]) ? al[t] : 0.0f;
            y0.y += (v0.y >= th[t]) ? al[t] : 0.0f;
            y0.z += (v0.z >= th[t]) ? al[t] : 0.0f;
            y0.w += (v0.w >= th[t]) ? al[t] : 0.0f;
            y1.x += (v1.x >= th[t]) ? al[t] : 0.0f;
            y1.y += (v1.y >= th[t]) ? al[t] : 0.0f;
            y1.z += (v1.z >= th[t]) ? al[t] : 0.0f;
            y1.w += (v1.w >= th[t]) ? al[t] : 0.0f;
        }
        __builtin_nontemporal_store(y0, &o4[i0]);
        __builtin_nontemporal_store(y1, &o4[i1]);
    } else {
        // Tail path (never taken for n = 32*4096*512, kept for safety).
        for (int i = i0; i < n4; i += blockDim.x) {
            fvec4 v = __builtin_nontemporal_load(&x4[i]);
            fvec4 y = {b, b, b, b};
#pragma unroll
            for (int t = 0; t < NUM_THRESHOLDS; ++t) {
                y.x += (v.x >= th[t]) ? al[t] : 0.0f;
                y.y += (v.y >= th[t]) ? al[t] : 0.0f;
                y.z += (v.z >= th[t]) ? al[t] : 0.0f;
                y.w += (v.w >= th[t]) ? al[t] : 0.0f;
            }
            __builtin_nontemporal_store(y, &o4[i]);
        }
    }
}

extern "C" void kernel_launch(void* const* d_in, const int* in_sizes, int n_in,
                              void* d_out, int out_size, void* d_ws, size_t ws_size,
                              hipStream_t stream) {
    // setup_inputs order: x, T, thresholds, alphas, b
    const float* x          = (const float*)d_in[0];
    // d_in[1] is T — only used in backward; unused here.
    const float* thresholds = (const float*)d_in[2];
    const float* alphas     = (const float*)d_in[3];
    const float* b          = (const float*)d_in[4];
    float* out              = (float*)d_out;

    const int n = in_sizes[0];          // 32*4096*512 = 67108864, divisible by 8
    const int n4 = n / 4;               // 16777216 fvec4 elements

    const int block = 256;
    const int per_block = block * 2;    // 2 fvec4 per thread
    const int grid = (n4 + per_block - 1) / per_block;  // 32768 blocks

    kmeans_quant_fwd<<<grid, block, 0, stream>>>(x, thresholds, alphas, b, out, n4);
}